// Round 6
// baseline (167.380 us; speedup 1.0000x reference)
//
#include <hip/hip_runtime.h>

#define KD 1536
#define ND 3072
#define MD 784
#define TT 16
#define NT (KD / 64)   // 24 K-tiles

typedef __attribute__((ext_vector_type(8))) short short8;
typedef __attribute__((ext_vector_type(4))) float floatx4;

__device__ __forceinline__ unsigned short f2bf(float f) {
    unsigned int x = __float_as_uint(f);
    unsigned int r = (x + 0x7fffu + ((x >> 16) & 1u)) >> 16;
    return (unsigned short)r;
}

__device__ __forceinline__ void gld_lds16(const unsigned short* g, unsigned short* l) {
    __builtin_amdgcn_global_load_lds((const __attribute__((address_space(1))) void*)g,
                                     (__attribute__((address_space(3))) void*)l, 16, 0, 0);
}

// =============== prep: packA (0..383) / packB (384..767). ROI lives in gemm epilogue. ===============
__global__ __launch_bounds__(256) void prep_k(const float* __restrict__ y,
                                              const float* __restrict__ conv_w,
                                              unsigned short* __restrict__ Ap,
                                              unsigned short* __restrict__ Bp) {
    __shared__ float sm[64 * 197];
    const int bid = blockIdx.x;
    const int tid = threadIdx.x;

    if (bid < 384) {
        // ---- packA: block = (t2, kc). float4 frame read into LDS, scatter even pixels as bf16.
        const int t2 = bid / 24, kc = bid % 24;
        for (int i4 = tid; i4 < 64 * 49; i4 += 256) {
            int c = i4 / 49, p4 = i4 % 49;
            float4 v = *(const float4*)(y + (size_t)(kc * 64 + c) * 3136 + t2 * 196 + p4 * 4);
            float* d = &sm[c * 197 + p4 * 4];
            d[0] = v.x; d[1] = v.y; d[2] = v.z; d[3] = v.w;
        }
        __syncthreads();
        for (int item = tid; item < 64 * 49; item += 256) {
            int c = item & 63, ij = item >> 6;
            int i = ij / 7, j = ij % 7;
            Ap[(size_t)(t2 * 49 + ij) * KD + kc * 64 + c] =
                f2bf(sm[c * 197 + (2 * i) * 14 + 2 * j]);
        }
    } else {
        // ---- packB: conv_w fp32 [o][c] -> bf16 [ND][KD], fully coalesced
        size_t base = (size_t)(bid - 384) * 12288;
#pragma unroll
        for (int v = 0; v < 12; ++v) {
            size_t e = base + v * 1024 + tid * 4;
            float4 w4 = *(const float4*)(conv_w + e);
            ushort4 o;
            o.x = f2bf(w4.x); o.y = f2bf(w4.y); o.z = f2bf(w4.z); o.w = f2bf(w4.w);
            *(ushort4*)(Bp + e) = o;
        }
        // no zerofill: gemm discards rows >= MD (poison there is benign)
    }
}

// =============== fused gemm: block = (64-ch chunk, t). 64x64 tile (49 valid rows), BK=64.
// K-loop: TRIPLE-buffered global_load_lds(16B) with COUNTED vmcnt (T4): per iter
//   s_waitcnt vmcnt(4)  (certify tile i, leave tile i+1's 4 DMAs in flight)
//   s_barrier; sched_barrier(0); issue stage(i+2); compute(i).
// WAR safety: stage(i+2) writes buf[(i+2)%3], last read in compute(i-1), which ALL
// waves finished before this barrier. vmcnt completes in order (m135), so vmcnt(4)
// certifies exactly the oldest stage. Last iter waits vmcnt(0).
// Epilogue: stage x_t frame tile into LDS (aliases dead staging bufs), bilinear ROI
// from LDS, BN + exact GELU + *mr in-register, scatter-ADD, write out.
// Rows 49..63 of the A tile are neighboring-t / poison rows; outputs discarded.
__global__ __launch_bounds__(256, 3) void gemm_k(const unsigned short* __restrict__ Ap,
                                                 const unsigned short* __restrict__ Bp,
                                                 const float* __restrict__ cb,
                                                 const float* __restrict__ gm,
                                                 const float* __restrict__ bt,
                                                 const float* __restrict__ rm,
                                                 const float* __restrict__ rv,
                                                 const float* __restrict__ x_t,
                                                 const float* __restrict__ rois,
                                                 float* __restrict__ out) {
    __shared__ float sm[64 * 197];   // 50,432 B; first 48 KB alias the 3x(A+B) staging buffers
    __shared__ float wx0s[14], wx1s[14], wy0s[14], wy1s[14];
    __shared__ int x0s[14], x1s[14], y0s[14], y1s[14], vxs[14], vys[14];

    unsigned short* const smem = (unsigned short*)sm;

    const int tid = threadIdx.x;
    const int n0 = blockIdx.x * 64;
    const int t = blockIdx.y;
    const int aRow0 = t * 49;
    const int wv = tid >> 6;
    const int lane = tid & 63;
    const int wm = wv >> 1, wn = wv & 1;
    const int l15 = lane & 15, quad = lane >> 4;
    const int prow = lane >> 3, pch = lane & 7;
    const int L = pch ^ (prow & 7);

    // ROI geometry params (read only in epilogue; K-loop barriers order them)
    if (tid < 14) {
        float b0 = rois[t * 4 + 0] * 0.0625f, b1 = rois[t * 4 + 1] * 0.0625f;
        float b2 = rois[t * 4 + 2] * 0.0625f, b3 = rois[t * 4 + 3] * 0.0625f;
        float rw = fmaxf(b2 - b0, 1.0f), rh = fmaxf(b3 - b1, 1.0f);
        float bw = rw * (1.0f / 7.0f), bh = rh * (1.0f / 7.0f);
        int p = tid;
        float pos = (float)(p >> 1) + 0.25f + 0.5f * (float)(p & 1);
        float xs = b0 + pos * bw;
        float ysv = b1 + pos * bh;
        vxs[p] = (xs >= -1.0f && xs <= 14.0f);
        vys[p] = (ysv >= -1.0f && ysv <= 14.0f);
        float xc = fminf(fmaxf(xs, 0.0f), 13.0f);
        float yc = fminf(fmaxf(ysv, 0.0f), 13.0f);
        int x0 = (int)floorf(xc), y0 = (int)floorf(yc);
        x0s[p] = x0; y0s[p] = y0;
        x1s[p] = min(x0 + 1, 13); y1s[p] = min(y0 + 1, 13);
        float lx = xc - (float)x0, ly = yc - (float)y0;
        wx0s[p] = 1.0f - lx; wx1s[p] = lx; wy0s[p] = 1.0f - ly; wy1s[p] = ly;
    }

    // Rotating tile buffers (wave-uniform scalar pointers, no arrays -> no scratch)
    unsigned short *A0 = smem,          *A1 = smem + 4096,  *A2 = smem + 8192;
    unsigned short *B0 = smem + 12288,  *B1 = smem + 16384, *B2 = smem + 20480;

    // staging: wv0 -> A rows 0..31, wv1 -> A rows 32..63, wv2 -> B rows 0..31, wv3 -> B rows 32..63
    // LDS dest is wave-uniform (+ hardware lane*16B); XOR-chunk swizzle in the global source addr.
    const unsigned short* gbase;
    int dstoff;
    if (wv < 2) {
        gbase = Ap + (size_t)(aRow0 + wv * 32 + prow) * KD + L * 8;
        dstoff = (wv * 32) * 64;
    } else {
        gbase = Bp + (size_t)(n0 + (wv - 2) * 32 + prow) * KD + L * 8;
        dstoff = ((wv - 2) * 32) * 64;
    }

    auto stage = [&](unsigned short* aT, unsigned short* bT, int kt) {
        unsigned short* dst = (wv < 2 ? aT : bT) + dstoff;
        const unsigned short* gb = gbase + kt;
#pragma unroll
        for (int j = 0; j < 4; ++j)
            gld_lds16(gb + (size_t)j * 8 * KD, dst + j * 512);
    };

    floatx4 acc[2][2];   // [mi][ni], static indexing only
    acc[0][0] = floatx4{0.f, 0.f, 0.f, 0.f};
    acc[0][1] = floatx4{0.f, 0.f, 0.f, 0.f};
    acc[1][0] = floatx4{0.f, 0.f, 0.f, 0.f};
    acc[1][1] = floatx4{0.f, 0.f, 0.f, 0.f};

    // prologue: prefetch tiles 0 and 1 (8 DMAs/wave outstanding)
    stage(A0, B0, 0);
    stage(A1, B1, 64);

    for (int i = 0; i < NT; ++i) {
        if (i < NT - 1)
            asm volatile("s_waitcnt vmcnt(4)" ::: "memory");
        else
            asm volatile("s_waitcnt vmcnt(0)" ::: "memory");
        __builtin_amdgcn_s_barrier();
        __builtin_amdgcn_sched_barrier(0);
        if (i + 2 < NT)
            stage(A2, B2, (i + 2) * 64);

        const unsigned short* Ab = A0;
        const unsigned short* Bb = B0;
#pragma unroll
        for (int ko = 0; ko < 2; ++ko) {
            int ch = ((ko * 4 + quad) ^ (l15 & 7)) * 8;  // phys chunk offset (ushorts)
            short8 a0 = *(const short8*)(Ab + (wm * 32 + l15) * 64 + ch);
            short8 a1 = *(const short8*)(Ab + (wm * 32 + 16 + l15) * 64 + ch);
            short8 b0 = *(const short8*)(Bb + (wn * 32 + l15) * 64 + ch);
            short8 b1 = *(const short8*)(Bb + (wn * 32 + 16 + l15) * 64 + ch);
            acc[0][0] = __builtin_amdgcn_mfma_f32_16x16x32_bf16(a0, b0, acc[0][0], 0, 0, 0);
            acc[0][1] = __builtin_amdgcn_mfma_f32_16x16x32_bf16(a0, b1, acc[0][1], 0, 0, 0);
            acc[1][0] = __builtin_amdgcn_mfma_f32_16x16x32_bf16(a1, b0, acc[1][0], 0, 0, 0);
            acc[1][1] = __builtin_amdgcn_mfma_f32_16x16x32_bf16(a1, b1, acc[1][1], 0, 0, 0);
        }

        // rotate buffers
        unsigned short* tA = A0; A0 = A1; A1 = A2; A2 = tA;
        unsigned short* tB = B0; B0 = B1; B1 = B2; B2 = tB;
    }

    // ---- epilogue phase 1: stage x_t frame tile (64ch x 196px) into sm (overwrites staging bufs)
    __syncthreads();                 // all waves done with K-loop LDS; all DMA drained (vmcnt(0) above)
    for (int i4 = tid; i4 < 64 * 49; i4 += 256) {
        int c = i4 / 49, p4 = i4 % 49;
        float4 xv = *(const float4*)(x_t + (size_t)(n0 + c) * 3136 + t * 196 + p4 * 4);
        float* d = &sm[c * 197 + p4 * 4];
        d[0] = xv.x; d[1] = xv.y; d[2] = xv.z; d[3] = xv.w;
    }
    __syncthreads();

    // ---- phase 2: per acc element compute mr (bilinear from sm), BN + GELU, w -> acc in place
#pragma unroll
    for (int ni = 0; ni < 2; ++ni) {
        const int cl = wn * 32 + ni * 16 + l15;
        const int n = n0 + cl;
        const float scale = gm[n] / sqrtf(rv[n] + 1e-6f);
        const float shift = (cb[n] - rm[n]) * scale + bt[n];
        const float* base = &sm[cl * 197];
#pragma unroll
        for (int mi = 0; mi < 2; ++mi) {
#pragma unroll
            for (int r = 0; r < 4; ++r) {
                const int m = wm * 32 + mi * 16 + quad * 4 + r;
                if (m < 49) {
                    const int i = m / 7, j = m % 7;
                    float sum = 0.0f;
#pragma unroll
                    for (int s = 0; s < 2; ++s) {
                        int pp = 2 * i + s;
#pragma unroll
                        for (int u = 0; u < 2; ++u) {
                            int q = 2 * j + u;
                            if (vys[pp] && vxs[q]) {
                                float v00 = base[y0s[pp] * 14 + x0s[q]];
                                float v01 = base[y0s[pp] * 14 + x1s[q]];
                                float v10 = base[y1s[pp] * 14 + x0s[q]];
                                float v11 = base[y1s[pp] * 14 + x1s[q]];
                                sum += wy0s[pp] * (wx0s[q] * v00 + wx1s[q] * v01) +
                                       wy1s[pp] * (wx0s[q] * v10 + wx1s[q] * v11);
                            }
                        }
                    }
                    const float mrv = 0.25f * sum;
                    const float v = acc[mi][ni][r] * scale + shift;
                    const float g = 0.5f * v * (1.0f + erff(v * 0.70710678118654752f));
                    acc[mi][ni][r] = g * mrv;
                }
            }
        }
    }
    __syncthreads();   // all bilinear reads of sm done before scatter-adds modify it

    // ---- phase 3: scatter-ADD w into the staged tile (distinct (pixel,channel) per element)
    float b0 = rois[t * 4 + 0] * 0.0625f, b1 = rois[t * 4 + 1] * 0.0625f;
    float b2 = rois[t * 4 + 2] * 0.0625f, b3 = rois[t * 4 + 3] * 0.0625f;
    int sxi = (int)floorf(b0), syi = (int)floorf(b1);
    int exi = (int)ceilf(b2), eyi = (int)ceilf(b3);
    int ml = (sxi + 7 < 14) ? sxi : exi - 7;
    int mt = (syi + 7 < 14) ? syi : eyi - 7;
    ml = min(max(ml, 0), 7);
    mt = min(max(mt, 0), 7);

#pragma unroll
    for (int ni = 0; ni < 2; ++ni) {
        const int cl = wn * 32 + ni * 16 + l15;
#pragma unroll
        for (int mi = 0; mi < 2; ++mi) {
#pragma unroll
            for (int r = 0; r < 4; ++r) {
                const int m = wm * 32 + mi * 16 + quad * 4 + r;
                if (m < 49) {
                    const int i = m / 7, j = m % 7;
                    sm[cl * 197 + (mt + i) * 14 + (ml + j)] += acc[mi][ni][r];
                }
            }
        }
    }
    __syncthreads();

    // ---- phase 4: write tile out = x_t + scatter(W), coalesced float4
    for (int i4 = tid; i4 < 64 * 49; i4 += 256) {
        int c = i4 / 49, p4 = i4 % 49;
        const float* d = &sm[c * 197 + p4 * 4];
        size_t e0 = (size_t)(n0 + c) * 3136 + t * 196 + p4 * 4;
        *(float4*)(out + e0) = make_float4(d[0], d[1], d[2], d[3]);
    }
}

extern "C" void kernel_launch(void* const* d_in, const int* in_sizes, int n_in,
                              void* d_out, int out_size, void* d_ws, size_t ws_size,
                              hipStream_t stream) {
    const float* y = (const float*)d_in[0];
    const float* x_t = (const float*)d_in[1];
    const float* rois = (const float*)d_in[2];
    const float* conv_w = (const float*)d_in[3];
    const float* cb = (const float*)d_in[4];
    const float* gm = (const float*)d_in[5];
    const float* bt = (const float*)d_in[6];
    const float* rm = (const float*)d_in[7];
    const float* rv = (const float*)d_in[8];
    float* out = (float*)d_out;

    char* ws = (char*)d_ws;
    unsigned short* Ap = (unsigned short*)ws;                 // 832*1536*2 B (rows >= 784 poison: staged for t=15 tile tail, outputs discarded)
    unsigned short* Bp = (unsigned short*)(ws + 2555904);     // 3072*1536*2 = 9,437,184 B

    prep_k<<<768, 256, 0, stream>>>(y, conv_w, Ap, Bp);
    gemm_k<<<dim3(ND / 64, TT), 256, 0, stream>>>(Ap, Bp, cb, gm, bt, rm, rv, x_t, rois, out);
}

// Round 7
// 166.042 us; speedup vs baseline: 1.0081x; 1.0081x over previous
//
#include <hip/hip_runtime.h>

#define KD 1536
#define ND 3072
#define MD 784
#define TT 16
#define NT (KD / 64)   // 24 K-tiles
#define PIT 204        // frame-tile pitch (floats): 16B-aligned rows, 204%32=12 -> 2/bank for l15 lanes

typedef __attribute__((ext_vector_type(8))) short short8;
typedef __attribute__((ext_vector_type(4))) float floatx4;

__device__ __forceinline__ unsigned short f2bf(float f) {
    unsigned int x = __float_as_uint(f);
    unsigned int r = (x + 0x7fffu + ((x >> 16) & 1u)) >> 16;
    return (unsigned short)r;
}

__device__ __forceinline__ void gld_lds16(const unsigned short* g, unsigned short* l) {
    __builtin_amdgcn_global_load_lds((const __attribute__((address_space(1))) void*)g,
                                     (__attribute__((address_space(3))) void*)l, 16, 0, 0);
}

// =============== prep: packA (0..383) / packB (384..767). ROI lives in gemm epilogue. ===============
__global__ __launch_bounds__(256) void prep_k(const float* __restrict__ y,
                                              const float* __restrict__ conv_w,
                                              unsigned short* __restrict__ Ap,
                                              unsigned short* __restrict__ Bp) {
    __shared__ __align__(16) float sm[64 * PIT];
    const int bid = blockIdx.x;
    const int tid = threadIdx.x;

    if (bid < 384) {
        // ---- packA: block = (t2, kc). float4 frame read -> ds_write_b128 (conflict-free),
        // scatter even pixels as bf16.
        const int t2 = bid / 24, kc = bid % 24;
        for (int i4 = tid; i4 < 64 * 49; i4 += 256) {
            int c = i4 / 49, p4 = i4 % 49;
            float4 v = *(const float4*)(y + (size_t)(kc * 64 + c) * 3136 + t2 * 196 + p4 * 4);
            *(float4*)(&sm[c * PIT + p4 * 4]) = v;
        }
        __syncthreads();
        for (int item = tid; item < 64 * 49; item += 256) {
            int c = item & 63, ij = item >> 6;
            int i = ij / 7, j = ij % 7;
            Ap[(size_t)(t2 * 49 + ij) * KD + kc * 64 + c] =
                f2bf(sm[c * PIT + (2 * i) * 14 + 2 * j]);
        }
    } else {
        // ---- packB: conv_w fp32 [o][c] -> bf16 [ND][KD], fully coalesced
        size_t base = (size_t)(bid - 384) * 12288;
#pragma unroll
        for (int v = 0; v < 12; ++v) {
            size_t e = base + v * 1024 + tid * 4;
            float4 w4 = *(const float4*)(conv_w + e);
            ushort4 o;
            o.x = f2bf(w4.x); o.y = f2bf(w4.y); o.z = f2bf(w4.z); o.w = f2bf(w4.w);
            *(ushort4*)(Bp + e) = o;
        }
        // no zerofill: gemm discards rows >= MD (poison there is benign)
    }
}

// =============== fused gemm: block = (64-ch chunk, t). 64x64 tile (49 valid rows), BK=64.
// K-loop: triple-buffered global_load_lds(16B), counted vmcnt(4) (verified r6, neutral-safe).
// Epilogue: stage x_t frame tile into LDS via float4/ds_*_b128 at pitch 204 (bank-clean),
// bilinear ROI from LDS, BN + exact GELU + *mr in-register, scatter-ADD, write out.
// Rows 49..63 of the A tile are neighboring-t / poison rows; outputs discarded.
__global__ __launch_bounds__(256, 3) void gemm_k(const unsigned short* __restrict__ Ap,
                                                 const unsigned short* __restrict__ Bp,
                                                 const float* __restrict__ cb,
                                                 const float* __restrict__ gm,
                                                 const float* __restrict__ bt,
                                                 const float* __restrict__ rm,
                                                 const float* __restrict__ rv,
                                                 const float* __restrict__ x_t,
                                                 const float* __restrict__ rois,
                                                 float* __restrict__ out) {
    __shared__ __align__(16) float sm[64 * PIT];   // 52,224 B; first 48 KB alias the 3x(A+B) staging bufs
    __shared__ float wx0s[14], wx1s[14], wy0s[14], wy1s[14];
    __shared__ int x0s[14], x1s[14], y0s[14], y1s[14], vxs[14], vys[14];

    unsigned short* const smem = (unsigned short*)sm;

    const int tid = threadIdx.x;
    const int n0 = blockIdx.x * 64;
    const int t = blockIdx.y;
    const int aRow0 = t * 49;
    const int wv = tid >> 6;
    const int lane = tid & 63;
    const int wm = wv >> 1, wn = wv & 1;
    const int l15 = lane & 15, quad = lane >> 4;
    const int prow = lane >> 3, pch = lane & 7;
    const int L = pch ^ (prow & 7);

    // ROI geometry params (read only in epilogue; K-loop barriers order them)
    if (tid < 14) {
        float b0 = rois[t * 4 + 0] * 0.0625f, b1 = rois[t * 4 + 1] * 0.0625f;
        float b2 = rois[t * 4 + 2] * 0.0625f, b3 = rois[t * 4 + 3] * 0.0625f;
        float rw = fmaxf(b2 - b0, 1.0f), rh = fmaxf(b3 - b1, 1.0f);
        float bw = rw * (1.0f / 7.0f), bh = rh * (1.0f / 7.0f);
        int p = tid;
        float pos = (float)(p >> 1) + 0.25f + 0.5f * (float)(p & 1);
        float xs = b0 + pos * bw;
        float ysv = b1 + pos * bh;
        vxs[p] = (xs >= -1.0f && xs <= 14.0f);
        vys[p] = (ysv >= -1.0f && ysv <= 14.0f);
        float xc = fminf(fmaxf(xs, 0.0f), 13.0f);
        float yc = fminf(fmaxf(ysv, 0.0f), 13.0f);
        int x0 = (int)floorf(xc), y0 = (int)floorf(yc);
        x0s[p] = x0; y0s[p] = y0;
        x1s[p] = min(x0 + 1, 13); y1s[p] = min(y0 + 1, 13);
        float lx = xc - (float)x0, ly = yc - (float)y0;
        wx0s[p] = 1.0f - lx; wx1s[p] = lx; wy0s[p] = 1.0f - ly; wy1s[p] = ly;
    }

    // Rotating tile buffers (wave-uniform scalar pointers, no arrays -> no scratch)
    unsigned short *A0 = smem,          *A1 = smem + 4096,  *A2 = smem + 8192;
    unsigned short *B0 = smem + 12288,  *B1 = smem + 16384, *B2 = smem + 20480;

    // staging: wv0 -> A rows 0..31, wv1 -> A rows 32..63, wv2 -> B rows 0..31, wv3 -> B rows 32..63
    // LDS dest is wave-uniform (+ hardware lane*16B); XOR-chunk swizzle in the global source addr.
    const unsigned short* gbase;
    int dstoff;
    if (wv < 2) {
        gbase = Ap + (size_t)(aRow0 + wv * 32 + prow) * KD + L * 8;
        dstoff = (wv * 32) * 64;
    } else {
        gbase = Bp + (size_t)(n0 + (wv - 2) * 32 + prow) * KD + L * 8;
        dstoff = ((wv - 2) * 32) * 64;
    }

    auto stage = [&](unsigned short* aT, unsigned short* bT, int kt) {
        unsigned short* dst = (wv < 2 ? aT : bT) + dstoff;
        const unsigned short* gb = gbase + kt;
#pragma unroll
        for (int j = 0; j < 4; ++j)
            gld_lds16(gb + (size_t)j * 8 * KD, dst + j * 512);
    };

    floatx4 acc[2][2];   // [mi][ni], static indexing only
    acc[0][0] = floatx4{0.f, 0.f, 0.f, 0.f};
    acc[0][1] = floatx4{0.f, 0.f, 0.f, 0.f};
    acc[1][0] = floatx4{0.f, 0.f, 0.f, 0.f};
    acc[1][1] = floatx4{0.f, 0.f, 0.f, 0.f};

    // prologue: prefetch tiles 0 and 1 (8 DMAs/wave outstanding)
    stage(A0, B0, 0);
    stage(A1, B1, 64);

    for (int i = 0; i < NT; ++i) {
        if (i < NT - 1)
            asm volatile("s_waitcnt vmcnt(4)" ::: "memory");
        else
            asm volatile("s_waitcnt vmcnt(0)" ::: "memory");
        __builtin_amdgcn_s_barrier();
        __builtin_amdgcn_sched_barrier(0);
        if (i + 2 < NT)
            stage(A2, B2, (i + 2) * 64);

        const unsigned short* Ab = A0;
        const unsigned short* Bb = B0;
#pragma unroll
        for (int ko = 0; ko < 2; ++ko) {
            int ch = ((ko * 4 + quad) ^ (l15 & 7)) * 8;  // phys chunk offset (ushorts)
            short8 a0 = *(const short8*)(Ab + (wm * 32 + l15) * 64 + ch);
            short8 a1 = *(const short8*)(Ab + (wm * 32 + 16 + l15) * 64 + ch);
            short8 b0 = *(const short8*)(Bb + (wn * 32 + l15) * 64 + ch);
            short8 b1 = *(const short8*)(Bb + (wn * 32 + 16 + l15) * 64 + ch);
            acc[0][0] = __builtin_amdgcn_mfma_f32_16x16x32_bf16(a0, b0, acc[0][0], 0, 0, 0);
            acc[0][1] = __builtin_amdgcn_mfma_f32_16x16x32_bf16(a0, b1, acc[0][1], 0, 0, 0);
            acc[1][0] = __builtin_amdgcn_mfma_f32_16x16x32_bf16(a1, b0, acc[1][0], 0, 0, 0);
            acc[1][1] = __builtin_amdgcn_mfma_f32_16x16x32_bf16(a1, b1, acc[1][1], 0, 0, 0);
        }

        // rotate buffers
        unsigned short* tA = A0; A0 = A1; A1 = A2; A2 = tA;
        unsigned short* tB = B0; B0 = B1; B1 = B2; B2 = tB;
    }

    // ---- epilogue phase 1: stage x_t frame tile (64ch x 196px) via float4 -> ds_write_b128
    __syncthreads();                 // all waves done with K-loop LDS; DMA drained (vmcnt(0) above)
    for (int i4 = tid; i4 < 64 * 49; i4 += 256) {
        int c = i4 / 49, p4 = i4 % 49;
        float4 xv = *(const float4*)(x_t + (size_t)(n0 + c) * 3136 + t * 196 + p4 * 4);
        *(float4*)(&sm[c * PIT + p4 * 4]) = xv;
    }
    __syncthreads();

    // ---- phase 2: per acc element compute mr (bilinear from sm), BN + GELU, w -> acc in place
#pragma unroll
    for (int ni = 0; ni < 2; ++ni) {
        const int cl = wn * 32 + ni * 16 + l15;
        const int n = n0 + cl;
        const float scale = gm[n] / sqrtf(rv[n] + 1e-6f);
        const float shift = (cb[n] - rm[n]) * scale + bt[n];
        const float* base = &sm[cl * PIT];
#pragma unroll
        for (int mi = 0; mi < 2; ++mi) {
#pragma unroll
            for (int r = 0; r < 4; ++r) {
                const int m = wm * 32 + mi * 16 + quad * 4 + r;
                if (m < 49) {
                    const int i = m / 7, j = m % 7;
                    float sum = 0.0f;
#pragma unroll
                    for (int s = 0; s < 2; ++s) {
                        int pp = 2 * i + s;
#pragma unroll
                        for (int u = 0; u < 2; ++u) {
                            int q = 2 * j + u;
                            if (vys[pp] && vxs[q]) {
                                float v00 = base[y0s[pp] * 14 + x0s[q]];
                                float v01 = base[y0s[pp] * 14 + x1s[q]];
                                float v10 = base[y1s[pp] * 14 + x0s[q]];
                                float v11 = base[y1s[pp] * 14 + x1s[q]];
                                sum += wy0s[pp] * (wx0s[q] * v00 + wx1s[q] * v01) +
                                       wy1s[pp] * (wx0s[q] * v10 + wx1s[q] * v11);
                            }
                        }
                    }
                    const float mrv = 0.25f * sum;
                    const float v = acc[mi][ni][r] * scale + shift;
                    const float g = 0.5f * v * (1.0f + erff(v * 0.70710678118654752f));
                    acc[mi][ni][r] = g * mrv;
                }
            }
        }
    }
    __syncthreads();   // all bilinear reads of sm done before scatter-adds modify it

    // ---- phase 3: scatter-ADD w into the staged tile (distinct (pixel,channel) per element)
    float b0 = rois[t * 4 + 0] * 0.0625f, b1 = rois[t * 4 + 1] * 0.0625f;
    float b2 = rois[t * 4 + 2] * 0.0625f, b3 = rois[t * 4 + 3] * 0.0625f;
    int sxi = (int)floorf(b0), syi = (int)floorf(b1);
    int exi = (int)ceilf(b2), eyi = (int)ceilf(b3);
    int ml = (sxi + 7 < 14) ? sxi : exi - 7;
    int mt = (syi + 7 < 14) ? syi : eyi - 7;
    ml = min(max(ml, 0), 7);
    mt = min(max(mt, 0), 7);

#pragma unroll
    for (int ni = 0; ni < 2; ++ni) {
        const int cl = wn * 32 + ni * 16 + l15;
#pragma unroll
        for (int mi = 0; mi < 2; ++mi) {
#pragma unroll
            for (int r = 0; r < 4; ++r) {
                const int m = wm * 32 + mi * 16 + quad * 4 + r;
                if (m < 49) {
                    const int i = m / 7, j = m % 7;
                    sm[cl * PIT + (mt + i) * 14 + (ml + j)] += acc[mi][ni][r];
                }
            }
        }
    }
    __syncthreads();

    // ---- phase 4: write tile out = x_t + scatter(W): ds_read_b128 -> coalesced float4 store
    for (int i4 = tid; i4 < 64 * 49; i4 += 256) {
        int c = i4 / 49, p4 = i4 % 49;
        float4 xv = *(const float4*)(&sm[c * PIT + p4 * 4]);
        size_t e0 = (size_t)(n0 + c) * 3136 + t * 196 + p4 * 4;
        *(float4*)(out + e0) = xv;
    }
}

extern "C" void kernel_launch(void* const* d_in, const int* in_sizes, int n_in,
                              void* d_out, int out_size, void* d_ws, size_t ws_size,
                              hipStream_t stream) {
    const float* y = (const float*)d_in[0];
    const float* x_t = (const float*)d_in[1];
    const float* rois = (const float*)d_in[2];
    const float* conv_w = (const float*)d_in[3];
    const float* cb = (const float*)d_in[4];
    const float* gm = (const float*)d_in[5];
    const float* bt = (const float*)d_in[6];
    const float* rm = (const float*)d_in[7];
    const float* rv = (const float*)d_in[8];
    float* out = (float*)d_out;

    char* ws = (char*)d_ws;
    unsigned short* Ap = (unsigned short*)ws;                 // 832*1536*2 B (rows >= 784 poison: staged for t=15 tile tail, outputs discarded)
    unsigned short* Bp = (unsigned short*)(ws + 2555904);     // 3072*1536*2 = 9,437,184 B

    prep_k<<<768, 256, 0, stream>>>(y, conv_w, Ap, Bp);
    gemm_k<<<dim3(ND / 64, TT), 256, 0, stream>>>(Ap, Bp, cb, gm, bt, rm, rv, x_t, rois, out);
}

// Round 8
// 161.301 us; speedup vs baseline: 1.0377x; 1.0294x over previous
//
#include <hip/hip_runtime.h>

#define KD 1536
#define ND 3072
#define MD 784
#define TT 16

typedef __attribute__((ext_vector_type(8))) short short8;
typedef __attribute__((ext_vector_type(4))) float floatx4;

__device__ __forceinline__ unsigned short f2bf(float f) {
    unsigned int x = __float_as_uint(f);
    unsigned int r = (x + 0x7fffu + ((x >> 16) & 1u)) >> 16;
    return (unsigned short)r;
}

__device__ __forceinline__ void gld_lds16(const unsigned short* g, unsigned short* l) {
    __builtin_amdgcn_global_load_lds((const __attribute__((address_space(1))) void*)g,
                                     (__attribute__((address_space(3))) void*)l, 16, 0, 0);
}

// =============== prep: packA (0..383) / packB (384..767). ROI lives in gemm epilogue. ===============
__global__ __launch_bounds__(256) void prep_k(const float* __restrict__ y,
                                              const float* __restrict__ conv_w,
                                              unsigned short* __restrict__ Ap,
                                              unsigned short* __restrict__ Bp) {
    __shared__ __align__(16) float sm[64 * 204];
    const int bid = blockIdx.x;
    const int tid = threadIdx.x;

    if (bid < 384) {
        // ---- packA: block = (t2, kc). float4 frame read -> ds_write_b128, scatter even pixels.
        const int t2 = bid / 24, kc = bid % 24;
        for (int i4 = tid; i4 < 64 * 49; i4 += 256) {
            int c = i4 / 49, p4 = i4 % 49;
            float4 v = *(const float4*)(y + (size_t)(kc * 64 + c) * 3136 + t2 * 196 + p4 * 4);
            *(float4*)(&sm[c * 204 + p4 * 4]) = v;
        }
        __syncthreads();
        for (int item = tid; item < 64 * 49; item += 256) {
            int c = item & 63, ij = item >> 6;
            int i = ij / 7, j = ij % 7;
            Ap[(size_t)(t2 * 49 + ij) * KD + kc * 64 + c] =
                f2bf(sm[c * 204 + (2 * i) * 14 + 2 * j]);
        }
    } else {
        // ---- packB: conv_w fp32 [o][c] -> bf16 [ND][KD], fully coalesced
        size_t base = (size_t)(bid - 384) * 12288;
#pragma unroll
        for (int v = 0; v < 12; ++v) {
            size_t e = base + v * 1024 + tid * 4;
            float4 w4 = *(const float4*)(conv_w + e);
            ushort4 o;
            o.x = f2bf(w4.x); o.y = f2bf(w4.y); o.z = f2bf(w4.z); o.w = f2bf(w4.w);
            *(ushort4*)(Bp + e) = o;
        }
        // no zerofill: gemm discards rows >= MD (poison there is benign)
    }
}

// =============== fused gemm: block = (32-ch chunk, t), 128 threads (2 waves), 1536 blocks.
// Wave tile 32x32 (read:MFMA = 1:1, per-CU LDS traffic unchanged vs 64x64/4-wave).
// LDS ~25.5 KB -> 6 blocks/CU resident: independent 2-wave blocks de-phase, so one
// block's VALU-heavy epilogue overlaps another's LDS-heavy K-loop (attacks the
// measured all-pipes-<30% lockstep). Plain dbuf K-loop (r3-proven; counted-vmcnt
// measured neutral in r6). ROI validity folded into zeroed weights (exact: 0*finite=0).
// Rows 49..63 of the A tile are neighboring-t / poison rows; outputs discarded.
__global__ __launch_bounds__(128, 3) void gemm_k(const unsigned short* __restrict__ Ap,
                                                 const unsigned short* __restrict__ Bp,
                                                 const float* __restrict__ cb,
                                                 const float* __restrict__ gm,
                                                 const float* __restrict__ bt,
                                                 const float* __restrict__ rm,
                                                 const float* __restrict__ rv,
                                                 const float* __restrict__ x_t,
                                                 const float* __restrict__ rois,
                                                 float* __restrict__ out) {
    __shared__ __align__(16) float sm[32 * 196];   // 25088 B; first 24 KB alias A/B double buffers
    __shared__ float wx0s[14], wx1s[14], wy0s[14], wy1s[14];
    __shared__ int x0s[14], x1s[14], y0s[14], y1s[14];

    unsigned short* const smem = (unsigned short*)sm;
    unsigned short* const As0 = smem;            // 64x64 ushorts = 8 KB
    unsigned short* const As1 = smem + 4096;
    unsigned short* const Bs0 = smem + 8192;     // 32x64 ushorts = 4 KB
    unsigned short* const Bs1 = smem + 10240;

    const int tid = threadIdx.x;
    const int n0 = blockIdx.x * 32;
    const int t = blockIdx.y;
    const int aRow0 = t * 49;
    const int wv = tid >> 6;          // 0..1
    const int lane = tid & 63;
    const int l15 = lane & 15, quad = lane >> 4;
    const int prow = lane >> 3, pch = lane & 7;
    const int L = pch ^ prow;         // XOR-chunk swizzle (row&7 == prow for all staged rows)

    // ROI geometry params; validity folded into weights (invalid -> 0, exact)
    if (tid < 14) {
        float b0 = rois[t * 4 + 0] * 0.0625f, b1 = rois[t * 4 + 1] * 0.0625f;
        float b2 = rois[t * 4 + 2] * 0.0625f, b3 = rois[t * 4 + 3] * 0.0625f;
        float rw = fmaxf(b2 - b0, 1.0f), rh = fmaxf(b3 - b1, 1.0f);
        float bw = rw * (1.0f / 7.0f), bh = rh * (1.0f / 7.0f);
        int p = tid;
        float pos = (float)(p >> 1) + 0.25f + 0.5f * (float)(p & 1);
        float xs = b0 + pos * bw;
        float ysv = b1 + pos * bh;
        bool vx = (xs >= -1.0f && xs <= 14.0f);
        bool vy = (ysv >= -1.0f && ysv <= 14.0f);
        float xc = fminf(fmaxf(xs, 0.0f), 13.0f);
        float yc = fminf(fmaxf(ysv, 0.0f), 13.0f);
        int x0 = (int)floorf(xc), y0 = (int)floorf(yc);
        x0s[p] = x0; y0s[p] = y0;
        x1s[p] = min(x0 + 1, 13); y1s[p] = min(y0 + 1, 13);
        float lx = xc - (float)x0, ly = yc - (float)y0;
        wx0s[p] = vx ? (1.0f - lx) : 0.0f; wx1s[p] = vx ? lx : 0.0f;
        wy0s[p] = vy ? (1.0f - ly) : 0.0f; wy1s[p] = vy ? ly : 0.0f;
    }

    // staging: wave wv -> A rows wv*32+(0..31) [4 calls], B rows wv*16+(0..15) [2 calls].
    // LDS dest wave-uniform (+ hardware lane*16B); swizzle in per-lane global source addr.
    const unsigned short* gA = Ap + (size_t)(aRow0 + wv * 32 + prow) * KD + L * 8;
    const unsigned short* gB = Bp + (size_t)(n0 + wv * 16 + prow) * KD + L * 8;

    auto stage = [&](unsigned short* aB, unsigned short* bB, int kt) {
#pragma unroll
        for (int v = 0; v < 4; ++v)
            gld_lds16(gA + (size_t)v * 8 * KD + kt, aB + wv * 2048 + v * 512);
#pragma unroll
        for (int v = 0; v < 2; ++v)
            gld_lds16(gB + (size_t)v * 8 * KD + kt, bB + wv * 1024 + v * 512);
    };

    floatx4 acc[2][2];   // [mi][ni], static indexing only
    acc[0][0] = floatx4{0.f, 0.f, 0.f, 0.f};
    acc[0][1] = floatx4{0.f, 0.f, 0.f, 0.f};
    acc[1][0] = floatx4{0.f, 0.f, 0.f, 0.f};
    acc[1][1] = floatx4{0.f, 0.f, 0.f, 0.f};

    stage(As0, Bs0, 0);
    int p = 0;
    for (int kt = 0; kt < KD; kt += 64, p ^= 1) {
        __syncthreads();   // drains DMA into buf p; orders vs prior reads of buf p^1
        if (kt + 64 < KD)
            stage(p ? As0 : As1, p ? Bs0 : Bs1, kt + 64);
        const unsigned short* Ab = p ? As1 : As0;
        const unsigned short* Bb = p ? Bs1 : Bs0;
#pragma unroll
        for (int ko = 0; ko < 2; ++ko) {
            int ch = ((ko * 4 + quad) ^ (l15 & 7)) * 8;  // phys chunk offset (ushorts)
            short8 a0 = *(const short8*)(Ab + (wv * 32 + l15) * 64 + ch);
            short8 a1 = *(const short8*)(Ab + (wv * 32 + 16 + l15) * 64 + ch);
            short8 b0 = *(const short8*)(Bb + (l15) * 64 + ch);
            short8 b1 = *(const short8*)(Bb + (16 + l15) * 64 + ch);
            acc[0][0] = __builtin_amdgcn_mfma_f32_16x16x32_bf16(a0, b0, acc[0][0], 0, 0, 0);
            acc[0][1] = __builtin_amdgcn_mfma_f32_16x16x32_bf16(a0, b1, acc[0][1], 0, 0, 0);
            acc[1][0] = __builtin_amdgcn_mfma_f32_16x16x32_bf16(a1, b0, acc[1][0], 0, 0, 0);
            acc[1][1] = __builtin_amdgcn_mfma_f32_16x16x32_bf16(a1, b1, acc[1][1], 0, 0, 0);
        }
    }

    // ---- epilogue phase 1: stage x_t frame tile (32ch x 196px) via float4 (overwrites dbuf)
    __syncthreads();                 // all waves done with K-loop LDS; DMA drained by barrier
    for (int i4 = tid; i4 < 32 * 49; i4 += 128) {
        int c = i4 / 49, p4 = i4 % 49;
        float4 xv = *(const float4*)(x_t + (size_t)(n0 + c) * 3136 + t * 196 + p4 * 4);
        *(float4*)(&sm[c * 196 + p4 * 4]) = xv;
    }
    __syncthreads();

    // ---- phase 2: per acc element compute mr (bilinear, zeroed-weight masking), BN+GELU, *mr
#pragma unroll
    for (int ni = 0; ni < 2; ++ni) {
        const int cl = ni * 16 + l15;            // 0..31
        const int n = n0 + cl;
        const float scale = gm[n] / sqrtf(rv[n] + 1e-6f);
        const float shift = (cb[n] - rm[n]) * scale + bt[n];
        const float* base = &sm[cl * 196];
#pragma unroll
        for (int mi = 0; mi < 2; ++mi) {
#pragma unroll
            for (int r = 0; r < 4; ++r) {
                const int m = wv * 32 + mi * 16 + quad * 4 + r;
                if (m < 49) {
                    const int i = m / 7, j = m % 7;
                    float sum = 0.0f;
#pragma unroll
                    for (int s = 0; s < 2; ++s) {
                        int pp = 2 * i + s;
#pragma unroll
                        for (int u = 0; u < 2; ++u) {
                            int q = 2 * j + u;
                            float v00 = base[y0s[pp] * 14 + x0s[q]];
                            float v01 = base[y0s[pp] * 14 + x1s[q]];
                            float v10 = base[y1s[pp] * 14 + x0s[q]];
                            float v11 = base[y1s[pp] * 14 + x1s[q]];
                            sum += wy0s[pp] * (wx0s[q] * v00 + wx1s[q] * v01) +
                                   wy1s[pp] * (wx0s[q] * v10 + wx1s[q] * v11);
                        }
                    }
                    const float mrv = 0.25f * sum;
                    const float v = acc[mi][ni][r] * scale + shift;
                    const float g = 0.5f * v * (1.0f + erff(v * 0.70710678118654752f));
                    acc[mi][ni][r] = g * mrv;
                }
            }
        }
    }
    __syncthreads();   // all bilinear reads of sm done before scatter-adds modify it

    // ---- phase 3: scatter-ADD w into the staged tile (distinct (pixel,channel) per element)
    float b0 = rois[t * 4 + 0] * 0.0625f, b1 = rois[t * 4 + 1] * 0.0625f;
    float b2 = rois[t * 4 + 2] * 0.0625f, b3 = rois[t * 4 + 3] * 0.0625f;
    int sxi = (int)floorf(b0), syi = (int)floorf(b1);
    int exi = (int)ceilf(b2), eyi = (int)ceilf(b3);
    int ml = (sxi + 7 < 14) ? sxi : exi - 7;
    int mt = (syi + 7 < 14) ? syi : eyi - 7;
    ml = min(max(ml, 0), 7);
    mt = min(max(mt, 0), 7);

#pragma unroll
    for (int ni = 0; ni < 2; ++ni) {
        const int cl = ni * 16 + l15;
#pragma unroll
        for (int mi = 0; mi < 2; ++mi) {
#pragma unroll
            for (int r = 0; r < 4; ++r) {
                const int m = wv * 32 + mi * 16 + quad * 4 + r;
                if (m < 49) {
                    const int i = m / 7, j = m % 7;
                    sm[cl * 196 + (mt + i) * 14 + (ml + j)] += acc[mi][ni][r];
                }
            }
        }
    }
    __syncthreads();

    // ---- phase 4: write tile out = x_t + scatter(W): LDS float4 -> coalesced global store
    for (int i4 = tid; i4 < 32 * 49; i4 += 128) {
        int c = i4 / 49, p4 = i4 % 49;
        float4 xv = *(const float4*)(&sm[c * 196 + p4 * 4]);
        size_t e0 = (size_t)(n0 + c) * 3136 + t * 196 + p4 * 4;
        *(float4*)(out + e0) = xv;
    }
}

extern "C" void kernel_launch(void* const* d_in, const int* in_sizes, int n_in,
                              void* d_out, int out_size, void* d_ws, size_t ws_size,
                              hipStream_t stream) {
    const float* y = (const float*)d_in[0];
    const float* x_t = (const float*)d_in[1];
    const float* rois = (const float*)d_in[2];
    const float* conv_w = (const float*)d_in[3];
    const float* cb = (const float*)d_in[4];
    const float* gm = (const float*)d_in[5];
    const float* bt = (const float*)d_in[6];
    const float* rm = (const float*)d_in[7];
    const float* rv = (const float*)d_in[8];
    float* out = (float*)d_out;

    char* ws = (char*)d_ws;
    unsigned short* Ap = (unsigned short*)ws;                 // 832*1536*2 B (rows >= 784 poison: staged for t=15 tile tail, outputs discarded)
    unsigned short* Bp = (unsigned short*)(ws + 2555904);     // 3072*1536*2 = 9,437,184 B

    prep_k<<<768, 256, 0, stream>>>(y, conv_w, Ap, Bp);
    gemm_k<<<dim3(ND / 32, TT), 128, 0, stream>>>(Ap, Bp, cb, gm, bt, rm, rv, x_t, rois, out);
}